// Round 3
// baseline (541.628 us; speedup 1.0000x reference)
//
#include <hip/hip_runtime.h>

#define TZ 128      // TOKEN_Z
#define JT 256      // j-tile per block
#define IT 4        // i-rows per block
#define R_MAX 32
#define S_MAX 2
#define NROW 139    // W rows: W_pos[0,66) W_tok[66,132) w_ent=132 W_ch[133,139)

typedef float v4f __attribute__((ext_vector_type(4)));

__global__ __launch_bounds__(256, 2) void relpos_kernel(
    const int* __restrict__ asym, const int* __restrict__ resi,
    const int* __restrict__ ent,  const int* __restrict__ tok,
    const int* __restrict__ sym,  const int* __restrict__ cyc,
    const float* __restrict__ W,  float* __restrict__ out, int L)
{
    __shared__ v4f sW[NROW * 32];          // 71,168 B — full W table
    __shared__ unsigned int sidx[IT * JT]; // 4 KB packed indices

    const int i0  = blockIdx.x * IT;
    const int j0  = blockIdx.y * JT;
    const int tid = threadIdx.x;

    const v4f* __restrict__ Wv = (const v4f*)W;

    // ---- stage W into LDS (once per block; L2-resident source) ----
    for (int idx = tid; idx < NROW * 32; idx += 256)
        sW[idx] = Wv[idx];

    // ---- phase 1: packed table indices for the IT x JT tile ----
    {
        const int j  = j0 + tid;
        const int aj = asym[j], rj = resi[j], ej = ent[j];
        const int tj = tok[j],  sj = sym[j],  cj = cyc[j];
        const int period = (cj > 0) ? cj : 10000;
        const float inv_p = 1.0f / (float)period;

        #pragma unroll
        for (int ii = 0; ii < IT; ++ii) {
            const int i  = i0 + ii;
            const int ai = asym[i], ri = resi[i], ei = ent[i];
            const int ti = tok[i],  si = sym[i];

            const bool same_chain = (ai == aj);
            const bool same_res   = (ri == rj);
            const bool same_ent   = (ei == ej);

            int rel = ri - rj;
            // jnp.round = round-half-even = rintf; astype(int32) truncates
            const float q = rintf((float)rel * inv_p);
            rel -= (int)((float)period * q);

            int dr = rel + R_MAX;
            dr = dr < 0 ? 0 : (dr > 2 * R_MAX ? 2 * R_MAX : dr);
            if (!same_chain) dr = 2 * R_MAX + 1;

            int dt = ti - tj + R_MAX;
            dt = dt < 0 ? 0 : (dt > 2 * R_MAX ? 2 * R_MAX : dt);
            if (!(same_chain && same_res)) dt = 2 * R_MAX + 1;

            int dc = si - sj + S_MAX;
            dc = dc < 0 ? 0 : (dc > 2 * S_MAX ? 2 * S_MAX : dc);
            if (same_chain) dc = 2 * S_MAX + 1;

            sidx[ii * JT + tid] = (unsigned)dr | ((unsigned)dt << 8)
                                | ((unsigned)dc << 16)
                                | ((unsigned)(same_ent ? 1u : 0u) << 24);
        }
    }

    // w_ent fragment into registers from global (overlaps with barrier)
    const int zq = tid & 31;   // float4 chunk of z
    const int jr = tid >> 5;   // 0..7
    const v4f we = Wv[132 * 32 + zq];

    __syncthreads();

    // ---- phase 2: LDS gathers + streaming stores ----
    for (int ii = 0; ii < IT; ++ii) {
        v4f* __restrict__ outp =
            (v4f*)(out + ((size_t)(i0 + ii) * (size_t)L + (size_t)j0) * TZ);

        #pragma unroll 4
        for (int it = 0; it < JT / 8; ++it) {
            const int jl = it * 8 + jr;
            const unsigned pk = sidx[ii * JT + jl];
            const int dr = pk & 0xFF;
            const int dt = (pk >> 8) & 0xFF;
            const int dc = (pk >> 16) & 0xFF;
            const float se = (pk >> 24) ? 1.0f : 0.0f;

            const v4f a = sW[dr * 32 + zq];
            const v4f b = sW[(66 + dt) * 32 + zq];
            const v4f c = sW[(133 + dc) * 32 + zq];

            const v4f r = a + b + c + se * we;

            // v4f index jl*32+zq = it*256+tid → block-contiguous 4 KB/iter
            __builtin_nontemporal_store(r, &outp[jl * 32 + zq]);
        }
    }
}

extern "C" void kernel_launch(void* const* d_in, const int* in_sizes, int n_in,
                              void* d_out, int out_size, void* d_ws, size_t ws_size,
                              hipStream_t stream) {
    const int* asym = (const int*)d_in[0];
    const int* resi = (const int*)d_in[1];
    const int* ent  = (const int*)d_in[2];
    const int* tok  = (const int*)d_in[3];
    const int* sym  = (const int*)d_in[4];
    const int* cyc  = (const int*)d_in[5];
    const float* W  = (const float*)d_in[6];
    float* out      = (float*)d_out;

    const int L = in_sizes[0];          // B=1, L=1024
    dim3 grid(L / IT, L / JT);
    dim3 block(256);
    relpos_kernel<<<grid, block, 0, stream>>>(asym, resi, ent, tok, sym, cyc, W, out, L);
}

// Round 4
// 534.415 us; speedup vs baseline: 1.0135x; 1.0135x over previous
//
#include <hip/hip_runtime.h>

#define TZ 128      // TOKEN_Z
#define JT 256      // j-tile per block
#define IT 4        // i-rows per block
#define R_MAX 32
#define S_MAX 2
#define NROW 139    // W rows: W_pos[0,66) W_tok[66,132) w_ent=132 W_ch[133,139)

typedef float v4f __attribute__((ext_vector_type(4)));

__global__ __launch_bounds__(256, 2) void relpos_kernel(
    const int* __restrict__ asym, const int* __restrict__ resi,
    const int* __restrict__ ent,  const int* __restrict__ tok,
    const int* __restrict__ sym,  const int* __restrict__ cyc,
    const float* __restrict__ W,  float* __restrict__ out, int L)
{
    __shared__ v4f sW[NROW * 32];          // 71,168 B — full W table
    __shared__ unsigned int sidx[IT * JT]; // 4 KB packed indices

    const int i0  = blockIdx.x * IT;
    const int j0  = blockIdx.y * JT;
    const int tid = threadIdx.x;

    const v4f* __restrict__ Wv = (const v4f*)W;

    // ---- stage W into LDS (once per block; L2-resident source) ----
    for (int idx = tid; idx < NROW * 32; idx += 256)
        sW[idx] = Wv[idx];

    // ---- phase 1: packed table indices for the IT x JT tile ----
    {
        const int j  = j0 + tid;
        const int aj = asym[j], rj = resi[j], ej = ent[j];
        const int tj = tok[j],  sj = sym[j],  cj = cyc[j];
        const int period = (cj > 0) ? cj : 10000;
        const float inv_p = 1.0f / (float)period;

        #pragma unroll
        for (int ii = 0; ii < IT; ++ii) {
            const int i  = i0 + ii;
            const int ai = asym[i], ri = resi[i], ei = ent[i];
            const int ti = tok[i],  si = sym[i];

            const bool same_chain = (ai == aj);
            const bool same_res   = (ri == rj);
            const bool same_ent   = (ei == ej);

            int rel = ri - rj;
            // jnp.round = round-half-even = rintf; astype(int32) truncates
            const float q = rintf((float)rel * inv_p);
            rel -= (int)((float)period * q);

            int dr = rel + R_MAX;
            dr = dr < 0 ? 0 : (dr > 2 * R_MAX ? 2 * R_MAX : dr);
            if (!same_chain) dr = 2 * R_MAX + 1;

            int dt = ti - tj + R_MAX;
            dt = dt < 0 ? 0 : (dt > 2 * R_MAX ? 2 * R_MAX : dt);
            if (!(same_chain && same_res)) dt = 2 * R_MAX + 1;

            int dc = si - sj + S_MAX;
            dc = dc < 0 ? 0 : (dc > 2 * S_MAX ? 2 * S_MAX : dc);
            if (same_chain) dc = 2 * S_MAX + 1;

            sidx[ii * JT + tid] = (unsigned)dr | ((unsigned)dt << 8)
                                | ((unsigned)dc << 16)
                                | ((unsigned)(same_ent ? 1u : 0u) << 24);
        }
    }

    // w_ent fragment into registers from global (overlaps with barrier)
    const int zq = tid & 31;   // float4 chunk of z
    const int jr = tid >> 5;   // 0..7
    const v4f we = Wv[132 * 32 + zq];

    __syncthreads();

    // ---- phase 2: LDS gathers + streaming (regular, write-back) stores ----
    for (int ii = 0; ii < IT; ++ii) {
        v4f* __restrict__ outp =
            (v4f*)(out + ((size_t)(i0 + ii) * (size_t)L + (size_t)j0) * TZ);

        #pragma unroll 4
        for (int it = 0; it < JT / 8; ++it) {
            const int jl = it * 8 + jr;
            const unsigned pk = sidx[ii * JT + jl];
            const int dr = pk & 0xFF;
            const int dt = (pk >> 8) & 0xFF;
            const int dc = (pk >> 16) & 0xFF;
            const float se = (pk >> 24) ? 1.0f : 0.0f;

            const v4f a = sW[dr * 32 + zq];
            const v4f b = sW[(66 + dt) * 32 + zq];
            const v4f c = sW[(133 + dc) * 32 + zq];

            // v4f index jl*32+zq = it*256+tid → block-contiguous 4 KB/iter
            outp[jl * 32 + zq] = a + b + c + se * we;
        }
    }
}

extern "C" void kernel_launch(void* const* d_in, const int* in_sizes, int n_in,
                              void* d_out, int out_size, void* d_ws, size_t ws_size,
                              hipStream_t stream) {
    const int* asym = (const int*)d_in[0];
    const int* resi = (const int*)d_in[1];
    const int* ent  = (const int*)d_in[2];
    const int* tok  = (const int*)d_in[3];
    const int* sym  = (const int*)d_in[4];
    const int* cyc  = (const int*)d_in[5];
    const float* W  = (const float*)d_in[6];
    float* out      = (float*)d_out;

    const int L = in_sizes[0];          // B=1, L=1024
    dim3 grid(L / IT, L / JT);
    dim3 block(256);
    relpos_kernel<<<grid, block, 0, stream>>>(asym, resi, ent, tok, sym, cyc, W, out, L);
}